// Round 1
// 360.773 us; speedup vs baseline: 1.0492x; 1.0492x over previous
//
#include <hip/hip_runtime.h>
#include <math.h>

// Problem constants (from reference setup_inputs)
#define BNUM 16
#define NNUM 4096
#define DNUM 1024
#define CNUM 4
#define HNUM 512

#define SCH   32              // N-chunks per bag
#define ROWS  (NNUM / SCH)    // 128 rows per workgroup
#define RPW   (ROWS / 4)      // 32 rows per wave (4 waves / 256-thread block)

#define NMAIN (SCH * BNUM)    // 512 mainpass blocks
#define NWEFFBLK 768
#define GRID1 (NMAIN + NWEFFBLK + 1)

// Workspace layout (in floats):
//  partials: [NMAIN] x PSTRIDE  {sum[1024], max[1024], acc[1024], m, l, pad}
//  Weff: [3*DNUM][4], bias[4]
#define PSTRIDE 3080
#define XOFF    ((size_t)NMAIN * PSTRIDE)
#define WOFF    (XOFF + 16)
#define BIASOFF (WOFF + (size_t)3 * DNUM * 4)

#define NEG_INF (-__builtin_inff())

typedef float vf4 __attribute__((ext_vector_type(4)));

// ---------------------------------------------------------------------------
// Stage 1. Blocks [0,NMAIN): streaming mainpass (proven inner loop; loads are
// nontemporal — bags is read-once and ~= L3 size, so don't thrash L2/L3).
// Blocks [NMAIN, NMAIN+768): Weff = W1@W2. Last block: bias = b1@W2 + b2 on
// wave 0, and wave 1 zeroes d_out (replaces the hipMemsetAsync dispatch —
// stream order guarantees completion before k_finish's atomics).
// ---------------------------------------------------------------------------
__global__ __launch_bounds__(256) void k_stage1(const float* __restrict__ bags,
                                                const float* __restrict__ query,
                                                const float* __restrict__ W1,
                                                const float* __restrict__ b1,
                                                const float* __restrict__ W2,
                                                const float* __restrict__ b2,
                                                float* __restrict__ ws,
                                                float* __restrict__ out) {
    const int tid  = threadIdx.x;
    const int wave = tid >> 6;
    const int lane = tid & 63;

    if (blockIdx.x >= NMAIN) {
        // ------------------- Weff / bias / out-zero path -------------------
        const vf4* w2 = (const vf4*)W2;
        const int wb = blockIdx.x - NMAIN;
        if (wb < NWEFFBLK) {
            const int k = wb * 4 + wave;
            const float* r = W1 + (size_t)k * HNUM;
            float a0 = 0.f, a1 = 0.f, a2 = 0.f, a3 = 0.f;
#pragma unroll
            for (int t = 0; t < 8; ++t) {
                const int j = lane * 8 + t;
                const float wv = r[j];
                const vf4   w  = w2[j];
                a0 += wv * w.x; a1 += wv * w.y; a2 += wv * w.z; a3 += wv * w.w;
            }
#pragma unroll
            for (int off = 32; off; off >>= 1) {
                a0 += __shfl_xor(a0, off, 64);
                a1 += __shfl_xor(a1, off, 64);
                a2 += __shfl_xor(a2, off, 64);
                a3 += __shfl_xor(a3, off, 64);
            }
            if (lane == 0) {
                vf4 rv; rv.x = a0; rv.y = a1; rv.z = a2; rv.w = a3;
                ((vf4*)(ws + WOFF))[k] = rv;
            }
        } else if (wave == 0) {
            float a0 = 0.f, a1 = 0.f, a2 = 0.f, a3 = 0.f;
#pragma unroll
            for (int t = 0; t < 8; ++t) {
                const int j = lane * 8 + t;
                const float bv = b1[j];
                const vf4   w  = w2[j];
                a0 += bv * w.x; a1 += bv * w.y; a2 += bv * w.z; a3 += bv * w.w;
            }
#pragma unroll
            for (int off = 32; off; off >>= 1) {
                a0 += __shfl_xor(a0, off, 64);
                a1 += __shfl_xor(a1, off, 64);
                a2 += __shfl_xor(a2, off, 64);
                a3 += __shfl_xor(a3, off, 64);
            }
            if (lane == 0) {
                float* bias = ws + BIASOFF;
                bias[0] = a0 + b2[0]; bias[1] = a1 + b2[1];
                bias[2] = a2 + b2[2]; bias[3] = a3 + b2[3];
            }
        } else if (wave == 1) {
            // zero the 64-float output (16 bags x 4 channels); one wave covers it
            out[lane] = 0.f;
        }
        return;
    }

    // ------------------- mainpass path -------------------
    const int chunk = blockIdx.x & (SCH - 1);
    const int b     = blockIdx.x >> 5;

    const vf4* q4 = (const vf4*)query;
    vf4 q[4];
#pragma unroll
    for (int s = 0; s < 4; ++s) q[s] = q4[s * 64 + lane];

    vf4 sum[4], mx[4], acc[4];
#pragma unroll
    for (int s = 0; s < 4; ++s) {
        sum[s] = (vf4)0.f;
        acc[s] = (vf4)0.f;
        mx[s]  = (vf4)NEG_INF;
    }
    float m = NEG_INF, l = 0.f;

    const int n0 = chunk * ROWS + wave * RPW;
    const vf4* base = (const vf4*)(bags + (size_t)b * NNUM * DNUM);

    for (int r = 0; r < RPW; r += 2) {
        const vf4* rowA = base + (size_t)(n0 + r) * (DNUM / 4);
        const vf4* rowB = rowA + (DNUM / 4);
        vf4 va[4], vb[4];
#pragma unroll
        for (int s = 0; s < 4; ++s) va[s] = __builtin_nontemporal_load(&rowA[s * 64 + lane]);
#pragma unroll
        for (int s = 0; s < 4; ++s) vb[s] = __builtin_nontemporal_load(&rowB[s * 64 + lane]);

        float pa = 0.f, pb = 0.f;
#pragma unroll
        for (int s = 0; s < 4; ++s) {
            pa += va[s].x * q[s].x + va[s].y * q[s].y + va[s].z * q[s].z + va[s].w * q[s].w;
            pb += vb[s].x * q[s].x + vb[s].y * q[s].y + vb[s].z * q[s].z + vb[s].w * q[s].w;
        }
#pragma unroll
        for (int off = 32; off; off >>= 1) {
            pa += __shfl_xor(pa, off, 64);
            pb += __shfl_xor(pb, off, 64);
        }

        // online softmax: wave-uniform, rarely-taken rescale
        const float mnew = fmaxf(m, fmaxf(pa, pb));
        if (mnew > m) {
            const float alpha = __expf(m - mnew);   // m=-inf first time -> 0
            l *= alpha;
#pragma unroll
            for (int s = 0; s < 4; ++s) acc[s] *= alpha;
            m = mnew;
        }
        const float wa = __expf(pa - m);
        const float wb = __expf(pb - m);
        l += wa + wb;

#pragma unroll
        for (int s = 0; s < 4; ++s) {
            sum[s] += va[s] + vb[s];
            mx[s].x = fmaxf(mx[s].x, fmaxf(va[s].x, vb[s].x));
            mx[s].y = fmaxf(mx[s].y, fmaxf(va[s].y, vb[s].y));
            mx[s].z = fmaxf(mx[s].z, fmaxf(va[s].z, vb[s].z));
            mx[s].w = fmaxf(mx[s].w, fmaxf(va[s].w, vb[s].w));
            acc[s] += wa * va[s] + wb * vb[s];
        }
    }

    // ---- block combine across 4 waves via reused 16KB LDS buffer ----
    __shared__ float buf[4][DNUM];
    __shared__ float sm[4], sl[4];
    if (lane == 0) { sm[wave] = m; sl[wave] = l; }

    float* wsp = ws + (size_t)(b * SCH + chunk) * PSTRIDE;

#pragma unroll
    for (int s = 0; s < 4; ++s) ((vf4*)(&buf[wave][s * 256]))[lane] = sum[s];
    __syncthreads();
    {
        vf4 a0 = ((vf4*)buf[0])[tid];
        vf4 a1 = ((vf4*)buf[1])[tid];
        vf4 a2 = ((vf4*)buf[2])[tid];
        vf4 a3 = ((vf4*)buf[3])[tid];
        ((vf4*)wsp)[tid] = a0 + a1 + a2 + a3;
    }
    __syncthreads();

#pragma unroll
    for (int s = 0; s < 4; ++s) ((vf4*)(&buf[wave][s * 256]))[lane] = mx[s];
    __syncthreads();
    {
        vf4 a0 = ((vf4*)buf[0])[tid];
        vf4 a1 = ((vf4*)buf[1])[tid];
        vf4 a2 = ((vf4*)buf[2])[tid];
        vf4 a3 = ((vf4*)buf[3])[tid];
        vf4 r;
        r.x = fmaxf(fmaxf(a0.x, a1.x), fmaxf(a2.x, a3.x));
        r.y = fmaxf(fmaxf(a0.y, a1.y), fmaxf(a2.y, a3.y));
        r.z = fmaxf(fmaxf(a0.z, a1.z), fmaxf(a2.z, a3.z));
        r.w = fmaxf(fmaxf(a0.w, a1.w), fmaxf(a2.w, a3.w));
        ((vf4*)(wsp + 1024))[tid] = r;
    }
    __syncthreads();

#pragma unroll
    for (int s = 0; s < 4; ++s) ((vf4*)(&buf[wave][s * 256]))[lane] = acc[s];
    __syncthreads();
    {
        const float m0 = sm[0], m1 = sm[1], m2 = sm[2], m3 = sm[3];
        const float mb = fmaxf(fmaxf(m0, m1), fmaxf(m2, m3));
        const float e0 = __expf(m0 - mb), e1 = __expf(m1 - mb);
        const float e2 = __expf(m2 - mb), e3 = __expf(m3 - mb);
        vf4 a0 = ((vf4*)buf[0])[tid];
        vf4 a1 = ((vf4*)buf[1])[tid];
        vf4 a2 = ((vf4*)buf[2])[tid];
        vf4 a3 = ((vf4*)buf[3])[tid];
        ((vf4*)(wsp + 2048))[tid] = a0 * e0 + a1 * e1 + a2 * e2 + a3 * e3;
        if (tid == 0) {
            wsp[3072] = mb;
            wsp[3073] = sl[0] * e0 + sl[1] * e1 + sl[2] * e2 + sl[3] * e3;
        }
    }
}

// ---------------------------------------------------------------------------
// Stage 2 (combine + head). Grid (BNUM, 16) = 256 blocks -> full-CU coverage
// (old version used 64 blocks = 25% of CUs, latency-bound chunk loop).
// Block (b, dg) owns 64 d's; each wave handles 8 of the 32 chunks, then a
// cross-wave LDS combine, Weff dot, 64-lane reduce, atomicAdd 4 channels.
// ---------------------------------------------------------------------------
__global__ __launch_bounds__(256) void k_finish(const float* __restrict__ ws,
                                                float* __restrict__ out) {
    const int b    = blockIdx.x;
    const int dg   = blockIdx.y;
    const int tid  = threadIdx.x;
    const int wave = tid >> 6, lane = tid & 63;
    const int d    = dg * 64 + lane;

    __shared__ float eS[SCH];
    __shared__ float lbS;
    __shared__ float sred[3][4][64];   // fs / fm / fa per wave

    const float* pbag = ws + (size_t)b * SCH * PSTRIDE;

    if (wave == 0) {
        const float* p = pbag + (size_t)(lane & (SCH - 1)) * PSTRIDE;
        const float mlane = (lane < SCH) ? p[3072] : NEG_INF;
        const float llane = (lane < SCH) ? p[3073] : 0.f;
        float mb = mlane;
#pragma unroll
        for (int off = 32; off; off >>= 1) mb = fmaxf(mb, __shfl_xor(mb, off, 64));
        const float e = __expf(mlane - mb);
        float lb = llane * e;
#pragma unroll
        for (int off = 32; off; off >>= 1) lb += __shfl_xor(lb, off, 64);
        if (lane < SCH) eS[lane] = e;
        if (lane == 0) lbS = lb;
    }
    __syncthreads();

    float fs = 0.f, fa = 0.f, fm = NEG_INF;
#pragma unroll
    for (int i = 0; i < 8; ++i) {
        const int c = wave * 8 + i;
        const float* p = pbag + (size_t)c * PSTRIDE;
        fs += p[d];
        fm = fmaxf(fm, p[1024 + d]);
        fa += eS[c] * p[2048 + d];
    }
    sred[0][wave][lane] = fs;
    sred[1][wave][lane] = fm;
    sred[2][wave][lane] = fa;
    __syncthreads();

    if (wave == 0) {
        fs = sred[0][0][lane] + sred[0][1][lane] + sred[0][2][lane] + sred[0][3][lane];
        fm = fmaxf(fmaxf(sred[1][0][lane], sred[1][1][lane]),
                   fmaxf(sred[1][2][lane], sred[1][3][lane]));
        fa = sred[2][0][lane] + sred[2][1][lane] + sred[2][2][lane] + sred[2][3][lane];

        const float xm = fs * (1.f / NNUM);
        const float xa = fa / lbS;

        const vf4* weff = (const vf4*)(ws + WOFF);
        const vf4 w0 = weff[d];
        const vf4 w1 = weff[DNUM + d];
        const vf4 w2 = weff[2 * DNUM + d];
        float c0 = xm * w0.x + fm * w1.x + xa * w2.x;
        float c1 = xm * w0.y + fm * w1.y + xa * w2.y;
        float c2 = xm * w0.z + fm * w1.z + xa * w2.z;
        float c3 = xm * w0.w + fm * w1.w + xa * w2.w;
#pragma unroll
        for (int off = 32; off; off >>= 1) {
            c0 += __shfl_xor(c0, off, 64);
            c1 += __shfl_xor(c1, off, 64);
            c2 += __shfl_xor(c2, off, 64);
            c3 += __shfl_xor(c3, off, 64);
        }
        if (lane == 0) {
            if (dg == 0) {
                const float* bias = ws + BIASOFF;
                c0 += bias[0]; c1 += bias[1]; c2 += bias[2]; c3 += bias[3];
            }
            atomicAdd(&out[b * 4 + 0], c0);
            atomicAdd(&out[b * 4 + 1], c1);
            atomicAdd(&out[b * 4 + 2], c2);
            atomicAdd(&out[b * 4 + 3], c3);
        }
    }
}

extern "C" void kernel_launch(void* const* d_in, const int* in_sizes, int n_in,
                              void* d_out, int out_size, void* d_ws, size_t ws_size,
                              hipStream_t stream) {
    const float* bags  = (const float*)d_in[0];
    const float* query = (const float*)d_in[1];
    const float* W1    = (const float*)d_in[2];
    const float* b1    = (const float*)d_in[3];
    const float* W2    = (const float*)d_in[4];
    const float* b2    = (const float*)d_in[5];
    float* out = (float*)d_out;
    float* ws  = (float*)d_ws;

    // d_out is poisoned 0xAA each call; k_stage1's tail block zeroes it
    // (stream order guarantees it lands before k_finish's atomicAdds),
    // removing the separate hipMemsetAsync dispatch.
    k_stage1<<<GRID1,          256, 0, stream>>>(bags, query, W1, b1, W2, b2, ws, out);
    k_finish<<<dim3(BNUM, 16), 256, 0, stream>>>(ws, out);
}